// Round 1
// baseline (500.273 us; speedup 1.0000x reference)
//
#include <hip/hip_runtime.h>
#include <stdint.h>

// Problem geometry (fixed by the reference): T=2048, B=32, H=64 -> 2048 cells.
#define T_STEPS 2048
#define N_CELLS 2048
#define CHUNK   128                       // timesteps per pipeline stage
#define NCHUNKS (T_STEPS / CHUNK)         // 16
#define GCELLS  64                        // cells per block (= threads per block)
#define NGROUPS (N_CELLS / GCELLS)        // 32
#define NBLOCKS (NCHUNKS * NGROUPS)       // 512 blocks; 64KB LDS each -> 2 blocks/CU -> fits 256 CUs
#define FLUX_ELEMS ((size_t)T_STEPS * N_CELLS * 4)  // 16,777,216 floats (start of states block)
#define NFLAGS ((NCHUNKS - 1) * NGROUPS)  // 480 handoff flags

__global__ void init_flags(int* flags) {
    int i = blockIdx.x * blockDim.x + threadIdx.x;
    if (i < NFLAGS) flags[i] = 0;
}

__global__ void __launch_bounds__(GCELLS) hydro_pipe(
    const float* __restrict__ forc,       // [T, 2048, 2]
    const float* __restrict__ init_state, // [2048, 2]
    const float* __restrict__ params,     // [2048, 4]
    float* __restrict__ out,              // fluxes [T,2048,4] ++ states [T,2048,2]
    int* __restrict__ flags)              // d_ws: [NCHUNKS-1][NGROUPS]
{
    // 128 steps x 64 cells x 2 floats = 64 KB
    __shared__ float4 sf4[CHUNK * (GCELLS * 2 / 4)];   // [CHUNK][32] float4

    const int b     = blockIdx.x;
    const int chunk = b / NGROUPS;        // chunk-major so chunk 0 dispatches first
    const int group = b % NGROUPS;
    const int tid   = threadIdx.x;        // 0..63
    const int cell  = group * GCELLS + tid;
    const int t0    = chunk * CHUNK;

    // ---- Phase 1: stage this block's forcings tile into LDS (all blocks in parallel,
    //      full-BW prefetch BEFORE the serial dependency arrives) ----
    {
        const float4* gf4 = (const float4*)forc;   // one t-row = 2048*2/4 = 1024 float4
        const int lane32 = tid & 31;
        const int half   = tid >> 5;               // threads 0-31 even row, 32-63 odd row
        #pragma unroll 8
        for (int it = 0; it < CHUNK / 2; ++it) {
            int row = it * 2 + half;
            sf4[row * 32 + lane32] =
                gf4[(size_t)(t0 + row) * (N_CELLS * 2 / 4) + group * 32 + lane32];
        }
    }

    // ---- per-cell parameters (physical transform, same constants/order as reference) ----
    const float4 u = ((const float4*)params)[cell];
    const float smax = 10.0f  + (500.0f - 10.0f ) * u.x;
    const float k1   = 0.01f  + (0.9f   - 0.01f ) * u.y;
    const float k2   = 0.001f + (0.2f   - 0.001f) * u.z;
    const float kb   = 0.001f + (0.1f   - 0.001f) * u.w;
    const float inv_smax = 1.0f / smax;

    float4* out_f = (float4*)out;                      // fluxes, float4 per (t,cell)
    float2* out_s = (float2*)(out + FLUX_ELEMS);       // states, float2 per (t,cell)

    // ---- Phase 2: acquire incoming state (pipeline handoff) ----
    float S1, S2;
    if (chunk == 0) {
        float2 s0 = ((const float2*)init_state)[cell];
        S1 = s0.x; S2 = s0.y;
    } else {
        const int fidx = (chunk - 1) * NGROUPS + group;
        // all threads spin with agent-scope acquire (invalidates L1 so the
        // subsequent plain state load is not stale)
        while (__hip_atomic_load(&flags[fidx], __ATOMIC_ACQUIRE,
                                 __HIP_MEMORY_SCOPE_AGENT) == 0) {
            __builtin_amdgcn_s_sleep(8);
        }
        float2 sp = out_s[(size_t)(t0 - 1) * N_CELLS + cell];  // states_seq[t0-1]
        S1 = sp.x; S2 = sp.y;
    }

    __syncthreads();   // staging by all threads complete before LDS reads

    // ---- serial recurrence over this chunk ----
    const float2* sfp = (const float2*)sf4;
    size_t fo = (size_t)t0 * N_CELLS + cell;   // index (t*2048+cell), works for both outputs
    #pragma unroll 4
    for (int r = 0; r < CHUNK; ++r) {
        float2 f = sfp[r * GCELLS + tid];
        float P = f.x, PET = f.y;
        float ratio = fminf(S1 * inv_smax, 1.0f);   // S1>=0 so lower clip is free
        float et   = PET * ratio;
        float q1   = k1 * S1;
        float perc = k2 * S1;
        float qb   = kb * S2;
        float S1n = fmaxf(S1 + P - et - q1 - perc, 0.0f);
        float S2n = fmaxf(S2 + perc - qb, 0.0f);
        out_f[fo] = make_float4(et, q1, perc, qb);
        out_s[fo] = make_float2(S1n, S2n);
        S1 = S1n; S2 = S2n;
        fo += N_CELLS;
    }

    // ---- publish chunk-end state (it is states_seq[t0+CHUNK-1], already stored) ----
    if (chunk < NCHUNKS - 1) {
        __threadfence();     // drain my stores to device scope
        __syncthreads();     // all threads fenced
        if (tid == 0)
            __hip_atomic_store(&flags[chunk * NGROUPS + group], 1,
                               __ATOMIC_RELEASE, __HIP_MEMORY_SCOPE_AGENT);
    }
}

extern "C" void kernel_launch(void* const* d_in, const int* in_sizes, int n_in,
                              void* d_out, int out_size, void* d_ws, size_t ws_size,
                              hipStream_t stream) {
    const float* forc = (const float*)d_in[0];
    const float* st0  = (const float*)d_in[1];
    const float* prm  = (const float*)d_in[2];
    float* out  = (float*)d_out;
    int* flags  = (int*)d_ws;   // needs only 1920 B of scratch

    hipLaunchKernelGGL(init_flags, dim3(2), dim3(256), 0, stream, flags);

    void* args[] = { (void*)&forc, (void*)&st0, (void*)&prm, (void*)&out, (void*)&flags };
    hipLaunchCooperativeKernel((const void*)hydro_pipe, dim3(NBLOCKS), dim3(GCELLS),
                               args, 0, stream);
}

// Round 2
// 291.195 us; speedup vs baseline: 1.7180x; 1.7180x over previous
//
#include <hip/hip_runtime.h>
#include <stdint.h>

// Geometry fixed by the reference: T=2048, B*H=2048 cells.
#define T_STEPS 2048
#define N_CELLS 2048
#define GCELLS  64                      // cells per group (= 1 wave)
#define NGROUPS (N_CELLS / GCELLS)      // 32
#define TS      64                      // pass-A LDS tile (timesteps)
#define NTILES  (T_STEPS / TS)          // 32
#define BCHUNK  32                      // pass-B chunk (timesteps)
#define NCHUNK  (T_STEPS / BCHUNK)      // 64
#define FLUX_ELEMS ((size_t)T_STEPS * N_CELLS * 4)

// Shared step math (MUST be bitwise-identical between pass A and pass B so the
// boundary elements pass A writes match what pass B's chunk recomputation
// would produce — makes the overlapping writes benign).
__device__ __forceinline__ void step_state(float& S1, float& S2,
                                           float P, float PET,
                                           float inv_smax, float a, float b,
                                           float k2) {
    float ratio = fminf(S1 * inv_smax, 1.0f);          // S1>=0 so low clip free
    float u1    = fmaf(S1, a, P);                      // S1*(1-k1-k2)+P
    float S1n   = fmaxf(fmaf(-PET, ratio, u1), 0.0f);  // - et, clamp
    float perc  = k2 * S1;
    float S2n   = fmaxf(fmaf(S2, b, perc), 0.0f);      // S2*(1-kb)+perc, clamp
    S1 = S1n; S2 = S2n;
}

// ---------------- Pass A: serial scan; writes only chunk-boundary states ----
// 32 blocks x 256 threads. Wave 0 = consumer (64 cells), waves 1..3 = LDS
// producers double-buffering 32KB forcing tiles.
__global__ void __launch_bounds__(256) hydro_scan(
    const float* __restrict__ forc,        // [T, 2048, 2]
    const float* __restrict__ init_state,  // [2048, 2]
    const float* __restrict__ params,      // [2048, 4]
    float* __restrict__ out)               // fluxes ++ states
{
    __shared__ float tile[2][TS * GCELLS * 2];   // 2 x 32 KB

    const int g    = blockIdx.x;     // group 0..31
    const int tid  = threadIdx.x;
    const int wave = tid >> 6;

    float2* out_s = (float2*)(out + FLUX_ELEMS);

    if (wave == 0) {
        // ---------------- consumer ----------------
        const int lane = tid;                    // 0..63
        const int cell = g * GCELLS + lane;
        const float4 u = ((const float4*)params)[cell];
        const float smax = 10.0f  + 490.0f * u.x;
        const float k1   = 0.01f  + 0.89f  * u.y;
        const float k2   = 0.001f + 0.199f * u.z;
        const float kb   = 0.001f + 0.099f * u.w;
        const float inv_smax = 1.0f / smax;
        const float a = 1.0f - k1 - k2;
        const float b = 1.0f - kb;
        float2 s0 = ((const float2*)init_state)[cell];
        float S1 = s0.x, S2 = s0.y;

        __syncthreads();                         // barrier #1: tile 0 staged
        for (int s = 0; s < NTILES; ++s) {
            const float2* tp = (const float2*)tile[s & 1];
            #pragma unroll 8
            for (int r = 0; r < TS; ++r) {
                float2 f = tp[r * GCELLS + lane];
                step_state(S1, S2, f.x, f.y, inv_smax, a, b, k2);
                int t = s * TS + r;
                // boundary state after step t feeds pass-B chunk (t+1)/32
                if (((t + 1) & (BCHUNK - 1)) == 0 && t != T_STEPS - 1)
                    out_s[(size_t)t * N_CELLS + cell] = make_float2(S1, S2);
            }
            __syncthreads();                     // barrier #2: next tile ready
        }
    } else {
        // ---------------- producers (waves 1..3) ----------------
        const int p = tid - 64;                  // 0..191
        const float4* gf = (const float4*)forc;  // one t-row = 1024 float4
        for (int s = 0; s < NTILES; ++s) {
            if (s == 0) {
                float4* dst = (float4*)tile[0];
                for (int i = p; i < TS * 32; i += 192) {
                    int row = i >> 5, col = i & 31;    // 32 float4 per row
                    dst[i] = gf[(size_t)row * 1024 + g * 32 + col];
                }
                __syncthreads();                 // barrier #1
            }
            if (s + 1 < NTILES) {
                float4* dst = (float4*)tile[(s + 1) & 1];
                const int t0 = (s + 1) * TS;
                for (int i = p; i < TS * 32; i += 192) {
                    int row = i >> 5, col = i & 31;
                    dst[i] = gf[(size_t)(t0 + row) * 1024 + g * 32 + col];
                }
            }
            __syncthreads();                     // barrier #2
        }
    }
}

// ---------------- Pass B: parallel chunk re-scan; writes everything ---------
// 2048 blocks x 64 threads: block = (chunk c, group g). Reads its boundary
// state (written by pass A, or init for c==0), recomputes 32 steps with the
// identical arithmetic, writes fluxes + states.
__global__ void __launch_bounds__(64) hydro_expand(
    const float* __restrict__ forc,
    const float* __restrict__ init_state,
    const float* __restrict__ params,
    float* __restrict__ out)
{
    const int blk = blockIdx.x;
    const int c   = blk >> 5;                // chunk 0..63 (same-c blocks adjacent)
    const int g   = blk & 31;
    const int tid = threadIdx.x;
    const int cell = g * GCELLS + tid;
    const int t0   = c * BCHUNK;

    float4* out_f = (float4*)out;
    float2* out_s = (float2*)(out + FLUX_ELEMS);

    const float4 u = ((const float4*)params)[cell];
    const float smax = 10.0f  + 490.0f * u.x;
    const float k1   = 0.01f  + 0.89f  * u.y;
    const float k2   = 0.001f + 0.199f * u.z;
    const float kb   = 0.001f + 0.099f * u.w;
    const float inv_smax = 1.0f / smax;
    const float a = 1.0f - k1 - k2;
    const float b = 1.0f - kb;

    float S1, S2;
    if (c == 0) {
        float2 s0 = ((const float2*)init_state)[cell];
        S1 = s0.x; S2 = s0.y;
    } else {
        float2 sp = out_s[(size_t)(t0 - 1) * N_CELLS + cell];
        S1 = sp.x; S2 = sp.y;
    }

    const float2* fp = (const float2*)forc;
    size_t idx = (size_t)t0 * N_CELLS + cell;     // valid for both outputs
    #pragma unroll 8
    for (int r = 0; r < BCHUNK; ++r) {
        float2 f = fp[idx];
        float P = f.x, PET = f.y;
        float ratio = fminf(S1 * inv_smax, 1.0f);
        float et    = PET * ratio;
        float q1    = k1 * S1;
        float perc  = k2 * S1;
        float qb    = kb * S2;
        // identical state math to pass A (bitwise)
        float u1  = fmaf(S1, a, P);
        float S1n = fmaxf(fmaf(-PET, ratio, u1), 0.0f);
        float S2n = fmaxf(fmaf(S2, b, perc), 0.0f);
        out_f[idx] = make_float4(et, q1, perc, qb);
        out_s[idx] = make_float2(S1n, S2n);
        S1 = S1n; S2 = S2n;
        idx += N_CELLS;
    }
}

extern "C" void kernel_launch(void* const* d_in, const int* in_sizes, int n_in,
                              void* d_out, int out_size, void* d_ws, size_t ws_size,
                              hipStream_t stream) {
    const float* forc = (const float*)d_in[0];
    const float* st0  = (const float*)d_in[1];
    const float* prm  = (const float*)d_in[2];
    float* out  = (float*)d_out;

    hipLaunchKernelGGL(hydro_scan, dim3(NGROUPS), dim3(256), 0, stream,
                       forc, st0, prm, out);
    hipLaunchKernelGGL(hydro_expand, dim3(NCHUNK * NGROUPS), dim3(GCELLS), 0, stream,
                       forc, st0, prm, out);
}

// Round 3
// 288.634 us; speedup vs baseline: 1.7332x; 1.0089x over previous
//
#include <hip/hip_runtime.h>
#include <stdint.h>

// Geometry fixed by the reference: T=2048, B*H=2048 cells.
#define T_STEPS 2048
#define N_CELLS 2048
#define GCELLS  64                      // cells per group (= 1 wave)
#define NGROUPS (N_CELLS / GCELLS)      // 32
#define TS      128                     // pass-A LDS tile (timesteps); 2x64KB dbuf
#define NTILES  (T_STEPS / TS)          // 16
#define BCHUNK  32                      // pass-B chunk (timesteps)
#define NCHUNK  (T_STEPS / BCHUNK)      // 64
#define FLUX_ELEMS ((size_t)T_STEPS * N_CELLS * 4)

// Step math — MUST be bitwise-identical between pass A and pass B so the
// boundary elements pass A writes match pass B's recomputation.
__device__ __forceinline__ void step_state(float& S1, float& S2,
                                           float P, float PET,
                                           float inv_smax, float a, float b,
                                           float k2) {
    float ratio = fminf(S1 * inv_smax, 1.0f);          // S1>=0, low clip free
    float u1    = fmaf(S1, a, P);                      // S1*(1-k1-k2)+P
    float S1n   = fmaxf(fmaf(-PET, ratio, u1), 0.0f);
    float perc  = k2 * S1;
    float S2n   = fmaxf(fmaf(S2, b, perc), 0.0f);
    S1 = S1n; S2 = S2n;
}

// ---------------- Pass A: serial scan; writes only chunk-boundary states ----
// 32 blocks x 256 threads. Wave 0 = consumer (64 cells, software-pipelined,
// BRANCH-FREE inner body), waves 1..3 = producers double-buffering 64KB tiles.
__global__ void __launch_bounds__(256) hydro_scan(
    const float* __restrict__ forc,        // [T, 2048, 2]
    const float* __restrict__ init_state,  // [2048, 2]
    const float* __restrict__ params,      // [2048, 4]
    float* __restrict__ out)               // fluxes ++ states
{
    __shared__ float tile[2][TS * GCELLS * 2];   // 2 x 64 KB = 128 KB (< 160)

    const int g    = blockIdx.x;     // group 0..31
    const int tid  = threadIdx.x;
    const int wave = tid >> 6;

    float2* out_s = (float2*)(out + FLUX_ELEMS);

    if (wave == 0) {
        // ---------------- consumer ----------------
        const int lane = tid;                    // 0..63
        const int cell = g * GCELLS + lane;
        const float4 u = ((const float4*)params)[cell];
        const float smax = 10.0f  + 490.0f * u.x;
        const float k1   = 0.01f  + 0.89f  * u.y;
        const float k2   = 0.001f + 0.199f * u.z;
        const float kb   = 0.001f + 0.099f * u.w;
        const float inv_smax = 1.0f / smax;
        const float a = 1.0f - k1 - k2;
        const float b = 1.0f - kb;
        float2 s0 = ((const float2*)init_state)[cell];
        float S1 = s0.x, S2 = s0.y;

        float2 buf[2][8];                        // 2-deep group pipeline

        __syncthreads();                         // barrier: tile 0 staged
        {
            const float2* tp = (const float2*)tile[0];
            #pragma unroll
            for (int j = 0; j < 8; ++j) buf[0][j] = tp[j * GCELLS + lane];
        }

        for (int s = 0; s < NTILES; ++s) {
            const float2* tp  = (const float2*)tile[s & 1];
            const float2* tpn = (const float2*)tile[(s + 1) & 1];
            #pragma unroll
            for (int grp = 0; grp < TS / 8; ++grp) {        // 16 groups, FULL unroll
                const int cur = grp & 1, nxt = cur ^ 1;
                if (grp < TS / 8 - 1) {                     // compile-time branch
                    #pragma unroll
                    for (int j = 0; j < 8; ++j)
                        buf[nxt][j] = tp[((grp + 1) * 8 + j) * GCELLS + lane];
                }
                #pragma unroll
                for (int j = 0; j < 8; ++j)
                    step_state(S1, S2, buf[cur][j].x, buf[cur][j].y,
                               inv_smax, a, b, k2);
                // boundary after step r = grp*8+7: (t+1)%32==0 <=> grp%4==3.
                // Compile-time under full unroll -> branch-free hot body.
                if ((grp & 3) == 3 && !(s == NTILES - 1 && grp == TS / 8 - 1)) {
                    int t = s * TS + grp * 8 + 7;
                    out_s[(size_t)t * N_CELLS + cell] = make_float2(S1, S2);
                }
            }
            __syncthreads();                     // producers staged tile s+1
            if (s < NTILES - 1) {
                #pragma unroll
                for (int j = 0; j < 8; ++j) buf[0][j] = tpn[j * GCELLS + lane];
            }
        }
    } else {
        // ---------------- producers (waves 1..3) ----------------
        const int p = tid - 64;                  // 0..191
        const float4* gf = (const float4*)forc;  // one t-row = 1024 float4
        {
            float4* dst = (float4*)tile[0];
            for (int i = p; i < TS * 32; i += 192) {
                int row = i >> 5, col = i & 31;  // 32 float4 per step-row
                dst[i] = gf[(size_t)row * 1024 + g * 32 + col];
            }
        }
        __syncthreads();                         // tile 0 staged
        for (int s = 0; s < NTILES; ++s) {
            if (s + 1 < NTILES) {
                float4* dst = (float4*)tile[(s + 1) & 1];
                const int t0 = (s + 1) * TS;
                for (int i = p; i < TS * 32; i += 192) {
                    int row = i >> 5, col = i & 31;
                    dst[i] = gf[(size_t)(t0 + row) * 1024 + g * 32 + col];
                }
            }
            __syncthreads();
        }
    }
}

// ---------------- Pass B: parallel chunk re-scan; writes everything ---------
// 2048 blocks x 64 threads: block = (chunk c, group g). Explicit 2-deep
// register pipeline on global forcing loads.
__global__ void __launch_bounds__(64) hydro_expand(
    const float* __restrict__ forc,
    const float* __restrict__ init_state,
    const float* __restrict__ params,
    float* __restrict__ out)
{
    const int blk = blockIdx.x;
    const int c   = blk >> 5;                // chunk 0..63
    const int g   = blk & 31;
    const int tid = threadIdx.x;
    const int cell = g * GCELLS + tid;
    const int t0   = c * BCHUNK;

    float4* out_f = (float4*)out;
    float2* out_s = (float2*)(out + FLUX_ELEMS);
    const float2* fp = (const float2*)forc;
    size_t idx = (size_t)t0 * N_CELLS + cell;

    // issue forcing preload + param/state loads before any dependent use
    float2 fbuf[2][8];
    #pragma unroll
    for (int j = 0; j < 8; ++j) fbuf[0][j] = fp[idx + (size_t)j * N_CELLS];

    const float4 u = ((const float4*)params)[cell];
    float S1, S2;
    if (c == 0) {
        float2 s0 = ((const float2*)init_state)[cell];
        S1 = s0.x; S2 = s0.y;
    } else {
        float2 sp = out_s[(size_t)(t0 - 1) * N_CELLS + cell];
        S1 = sp.x; S2 = sp.y;
    }
    const float smax = 10.0f  + 490.0f * u.x;
    const float k1   = 0.01f  + 0.89f  * u.y;
    const float k2   = 0.001f + 0.199f * u.z;
    const float kb   = 0.001f + 0.099f * u.w;
    const float inv_smax = 1.0f / smax;
    const float a = 1.0f - k1 - k2;
    const float b = 1.0f - kb;

    #pragma unroll
    for (int grp = 0; grp < BCHUNK / 8; ++grp) {      // 4 groups, full unroll
        const int cur = grp & 1, nxt = cur ^ 1;
        if (grp < BCHUNK / 8 - 1) {                   // compile-time
            #pragma unroll
            for (int j = 0; j < 8; ++j)
                fbuf[nxt][j] = fp[idx + (size_t)((grp + 1) * 8 + j) * N_CELLS];
        }
        #pragma unroll
        for (int j = 0; j < 8; ++j) {
            float2 f = fbuf[cur][j];
            float P = f.x, PET = f.y;
            float ratio = fminf(S1 * inv_smax, 1.0f);
            float et    = PET * ratio;
            float q1    = k1 * S1;
            float perc  = k2 * S1;
            float qb    = kb * S2;
            float u1  = fmaf(S1, a, P);               // identical to pass A
            float S1n = fmaxf(fmaf(-PET, ratio, u1), 0.0f);
            float S2n = fmaxf(fmaf(S2, b, perc), 0.0f);
            size_t o = idx + (size_t)(grp * 8 + j) * N_CELLS;
            out_f[o] = make_float4(et, q1, perc, qb);
            out_s[o] = make_float2(S1n, S2n);
            S1 = S1n; S2 = S2n;
        }
    }
}

extern "C" void kernel_launch(void* const* d_in, const int* in_sizes, int n_in,
                              void* d_out, int out_size, void* d_ws, size_t ws_size,
                              hipStream_t stream) {
    const float* forc = (const float*)d_in[0];
    const float* st0  = (const float*)d_in[1];
    const float* prm  = (const float*)d_in[2];
    float* out  = (float*)d_out;

    hipLaunchKernelGGL(hydro_scan, dim3(NGROUPS), dim3(256), 0, stream,
                       forc, st0, prm, out);
    hipLaunchKernelGGL(hydro_expand, dim3(NCHUNK * NGROUPS), dim3(GCELLS), 0, stream,
                       forc, st0, prm, out);
}

// Round 4
// 186.993 us; speedup vs baseline: 2.6754x; 1.5436x over previous
//
#include <hip/hip_runtime.h>
#include <stdint.h>

// Geometry fixed by the reference: T=2048, B*H=2048 cells.
#define T_STEPS 2048
#define N_CELLS 2048
#define GCELLS  64                      // cells per scan group (= 1 wave)
#define NGROUPS (N_CELLS / GCELLS)      // 32
#define TS      128                     // scan LDS tile (timesteps); 2x64KB dbuf
#define NTILES  (T_STEPS / TS)          // 16
#define BCHUNK  16                      // expand chunk (timesteps)
#define NCHUNK  (T_STEPS / BCHUNK)      // 128
#define FLUX_ELEMS ((size_t)T_STEPS * N_CELLS * 4)

#define AS3 __attribute__((address_space(3)))
#define AS1 __attribute__((address_space(1)))

// Step math — bitwise-identical between scan and expand so the boundary
// elements scan writes match expand's recomputation exactly.
__device__ __forceinline__ void step_state(float& S1, float& S2,
                                           float P, float PET,
                                           float inv_smax, float a, float b,
                                           float k2) {
    float ratio = fminf(S1 * inv_smax, 1.0f);          // S1>=0, low clip free
    float u1    = fmaf(S1, a, P);                      // S1*(1-k1-k2)+P
    float S1n   = fmaxf(fmaf(-PET, ratio, u1), 0.0f);
    float perc  = k2 * S1;
    float S2n   = fmaxf(fmaf(S2, b, perc), 0.0f);
    S1 = S1n; S2 = S2n;
}

// ---------------- Pass A: serial scan, async LDS staging ----------------
// 32 blocks x 64 threads (ONE wave). The wave issues 64 global_load_lds
// (16B/lane -> 1KB/instr, all in flight) for tile s+1, computes tile s,
// then a single s_waitcnt vmcnt(0). No __syncthreads anywhere.
__global__ void __launch_bounds__(64) hydro_scan(
    const float* __restrict__ forc,        // [T, 2048, 2]
    const float* __restrict__ init_state,  // [2048, 2]
    const float* __restrict__ params,      // [2048, 4]
    float* __restrict__ out)               // fluxes ++ states
{
    __shared__ float4 tile[2][TS * 32];    // 2 x 64 KB

    const int g    = blockIdx.x;           // group 0..31
    const int L    = threadIdx.x;          // lane 0..63
    const int cell = g * GCELLS + L;

    float2* out_s = (float2*)(out + FLUX_ELEMS);

    // per-lane global base (float4 units). One t-row = 1024 float4; each
    // instr covers rows 2k (lanes 0-31) and 2k+1 (lanes 32-63), cols g*32..+31.
    const float4* gf4 = (const float4*)forc;
    const size_t lane_off = (size_t)(L >> 5) * 1024 + (size_t)g * 32 + (L & 31);

    // params / init state (issued early, independent)
    const float4 u = ((const float4*)params)[cell];
    float2 s0 = ((const float2*)init_state)[cell];

    // ---- stage tile 0 (async), wait ----
    {
        const float4* gp = gf4 + lane_off;
        AS3 char* lp = (AS3 char*)(void*)tile[0];
        #pragma unroll
        for (int k = 0; k < 64; ++k)
            __builtin_amdgcn_global_load_lds((AS1 const void*)(gp + (size_t)k * 2048),
                                             (AS3 void*)(lp + (size_t)k * 1024),
                                             16, 0, 0);
    }

    const float smax = 10.0f  + 490.0f * u.x;
    const float k1   = 0.01f  + 0.89f  * u.y;
    const float k2   = 0.001f + 0.199f * u.z;
    const float kb   = 0.001f + 0.099f * u.w;
    const float inv_smax = 1.0f / smax;
    const float a = 1.0f - k1 - k2;
    const float b = 1.0f - kb;
    float S1 = s0.x, S2 = s0.y;

    asm volatile("s_waitcnt vmcnt(0)" ::: "memory");   // tile 0 resident

    for (int s = 0; s < NTILES; ++s) {
        // ---- issue async staging for tile s+1 (fire and forget) ----
        if (s + 1 < NTILES) {
            const float4* gp = gf4 + (size_t)(s + 1) * TS * 1024 + lane_off;
            AS3 char* lp = (AS3 char*)(void*)tile[(s + 1) & 1];
            #pragma unroll
            for (int k = 0; k < 64; ++k)
                __builtin_amdgcn_global_load_lds((AS1 const void*)(gp + (size_t)k * 2048),
                                                 (AS3 void*)(lp + (size_t)k * 1024),
                                                 16, 0, 0);
        }

        // ---- compute tile s (2-deep group pipeline, branch-free body) ----
        const float2* tp = (const float2*)tile[s & 1];
        float2 buf[2][8];
        #pragma unroll
        for (int j = 0; j < 8; ++j) buf[0][j] = tp[j * GCELLS + L];

        #pragma unroll
        for (int grp = 0; grp < TS / 8; ++grp) {       // 16 groups, full unroll
            const int cur = grp & 1, nxt = cur ^ 1;
            if (grp < TS / 8 - 1) {                    // compile-time branch
                #pragma unroll
                for (int j = 0; j < 8; ++j)
                    buf[nxt][j] = tp[((grp + 1) * 8 + j) * GCELLS + L];
            }
            #pragma unroll
            for (int j = 0; j < 8; ++j)
                step_state(S1, S2, buf[cur][j].x, buf[cur][j].y,
                           inv_smax, a, b, k2);
            // boundary after step t = s*128+grp*8+7; (t+1)%16==0 <=> grp odd
            if ((grp & 1) == 1 && !(s == NTILES - 1 && grp == TS / 8 - 1)) {
                int t = s * TS + grp * 8 + 7;
                out_s[(size_t)t * N_CELLS + cell] = make_float2(S1, S2);
            }
        }

        // ---- tile s+1 data must be in LDS before next iteration reads it ----
        asm volatile("s_waitcnt vmcnt(0)" ::: "memory");
    }
}

// ---------------- Pass B: parallel chunk re-scan; writes everything ---------
// 1024 blocks x 256 threads = 4096 independent waves (16 waves/CU).
// wave = (chunk c, group g): preload ALL 16 forcings into registers (fully
// in flight), read boundary state, recompute 16 steps bitwise-identically,
// write fluxes + states.
__global__ void __launch_bounds__(256) hydro_expand(
    const float* __restrict__ forc,
    const float* __restrict__ init_state,
    const float* __restrict__ params,
    float* __restrict__ out)
{
    const int blk  = blockIdx.x;
    const int wave = threadIdx.x >> 6;
    const int L    = threadIdx.x & 63;
    const int c    = blk >> 3;                 // chunk 0..127
    const int g    = (blk & 7) * 4 + wave;     // group 0..31
    const int cell = g * GCELLS + L;
    const int t0   = c * BCHUNK;

    float4* out_f = (float4*)out;
    float2* out_s = (float2*)(out + FLUX_ELEMS);
    const float2* fp = (const float2*)forc;
    size_t idx = (size_t)t0 * N_CELLS + cell;

    // all 16 forcing loads in flight before any dependent use
    float2 fb[BCHUNK];
    #pragma unroll
    for (int j = 0; j < BCHUNK; ++j) fb[j] = fp[idx + (size_t)j * N_CELLS];

    const float4 u = ((const float4*)params)[cell];
    float2 sp = (c == 0) ? ((const float2*)init_state)[cell]
                         : out_s[(size_t)(t0 - 1) * N_CELLS + cell];

    const float smax = 10.0f  + 490.0f * u.x;
    const float k1   = 0.01f  + 0.89f  * u.y;
    const float k2   = 0.001f + 0.199f * u.z;
    const float kb   = 0.001f + 0.099f * u.w;
    const float inv_smax = 1.0f / smax;
    const float a = 1.0f - k1 - k2;
    const float b = 1.0f - kb;
    float S1 = sp.x, S2 = sp.y;

    #pragma unroll
    for (int j = 0; j < BCHUNK; ++j) {
        float P = fb[j].x, PET = fb[j].y;
        float ratio = fminf(S1 * inv_smax, 1.0f);
        float et    = PET * ratio;
        float q1    = k1 * S1;
        float perc  = k2 * S1;
        float qb    = kb * S2;
        float u1  = fmaf(S1, a, P);                // identical to scan (bitwise)
        float S1n = fmaxf(fmaf(-PET, ratio, u1), 0.0f);
        float S2n = fmaxf(fmaf(S2, b, perc), 0.0f);
        size_t o = idx + (size_t)j * N_CELLS;
        out_f[o] = make_float4(et, q1, perc, qb);
        out_s[o] = make_float2(S1n, S2n);
        S1 = S1n; S2 = S2n;
    }
}

extern "C" void kernel_launch(void* const* d_in, const int* in_sizes, int n_in,
                              void* d_out, int out_size, void* d_ws, size_t ws_size,
                              hipStream_t stream) {
    const float* forc = (const float*)d_in[0];
    const float* st0  = (const float*)d_in[1];
    const float* prm  = (const float*)d_in[2];
    float* out  = (float*)d_out;

    hipLaunchKernelGGL(hydro_scan, dim3(NGROUPS), dim3(GCELLS), 0, stream,
                       forc, st0, prm, out);
    hipLaunchKernelGGL(hydro_expand, dim3(NCHUNK * NGROUPS / 4), dim3(256), 0, stream,
                       forc, st0, prm, out);
}